// Round 12
// baseline (445.655 us; speedup 1.0000x reference)
//
#include <hip/hip_runtime.h>
#include <hip/hip_bf16.h>
#include <math.h>

#define H 128
#define K 20
#define EPB 16        // edges per block (M=16 for MFMA)

// ---- workspace layout (float offsets) ----
#define WS_TBL    0            // merged table: 257 rows x 256 floats {W,B}
#define WS_THM    65792        // 256 merged sorted thresholds
#define WS_CNT    66176        // 1 int: M = nP + nN
#define WSB_HI    67072        // 65536 ushort: em_w1 bf16-hi, B-fragment order
#define WSB_LO    99840        // 65536 ushort: em_w1 bf16-lo

typedef __attribute__((ext_vector_type(8))) short short8;
typedef __attribute__((ext_vector_type(4))) float f32x4;

// DPP-based wave64 sum; result valid in lane 63.
template<int CTRL, int RMASK>
__device__ __forceinline__ float dpp_add(float x) {
  int y = __builtin_amdgcn_update_dpp(0, __float_as_int(x), CTRL, RMASK, 0xf, true);
  return x + __int_as_float(y);
}
__device__ __forceinline__ float wave_sum63(float x) {
  x = dpp_add<0xB1,  0xf>(x);
  x = dpp_add<0x4E,  0xf>(x);
  x = dpp_add<0x141, 0xf>(x);
  x = dpp_add<0x140, 0xf>(x);
  x = dpp_add<0x142, 0xa>(x);
  x = dpp_add<0x143, 0xc>(x);
  return x;
}
__device__ __forceinline__ float bcast63(float x) {
  return __int_as_float(__builtin_amdgcn_readlane(__float_as_int(x), 63));
}

__device__ __forceinline__ unsigned short bfbits(float x) {
  __hip_bfloat16 h = __float2bfloat16(x);
  unsigned short u; __builtin_memcpy(&u, &h, 2); return u;
}
__device__ __forceinline__ float bf2f(unsigned short u) {
  return __uint_as_float(((unsigned)u) << 16);
}

// Single fused aux kernel (769 blocks x 128 threads):
//  blocks 0..256  : locally recompute the threshold sort, then build merged-
//                   table row r = blockIdx (block 0 also publishes THM/CNT).
//  blocks 257..768: pack em_w1 into bf16 hi/lo planes, B-fragment order.
__global__ __launch_bounds__(128) void aux_kernel(
    const float* __restrict__ w1v, const float* __restrict__ b1v,
    const float* __restrict__ w2, const float* __restrict__ b2,
    const float* __restrict__ em_w1, float* __restrict__ ws)
{
  int blk = blockIdx.x;
  int tid = threadIdx.x;
  if (blk < 257) {
    __shared__ float th[H];
    __shared__ int grp[H];
    __shared__ int sidx[2 * H];
    __shared__ int Msh;
    float w = w1v[tid], b = b1v[tid];
    int g = (w > 0.f) ? 0 : ((w < 0.f) ? 1 : 2);   // 0=P, 1=N, 2=Z
    float t = (g == 2) ? 0.f : (-b / w);
    th[tid] = t; grp[tid] = g;
    if (tid == 0) Msh = 0;
    __syncthreads();
    if (g != 2) {
      int r = 0;
      for (int i = 0; i < H; i++)
        if (grp[i] != 2 && (th[i] < t || (th[i] == t && i < tid))) r++;
      sidx[r] = (tid << 1) | (g == 0 ? 1 : 0);     // bit0 = isP
      atomicAdd(&Msh, 1);
      if (blk == 0) ws[WS_THM + r] = t;            // publish for main
    }
    __syncthreads();
    int M = Msh;
    if (blk == 0 && tid == 0) ((int*)(ws + WS_CNT))[0] = M;
    int r = blk;
    if (r > M) return;
    int d = tid;
    // BASE[d] = tp_b2[d] + sum over (w1==0, b1>0) of b1*w2[h][d]
    float accW = 0.f, accB = b2[d];
    for (int i = 0; i < H; i++)
      if (grp[i] == 2 && b1v[i] > 0.f) accB += b1v[i] * w2[i * H + d];
    #pragma unroll 4
    for (int i = 0; i < M; i++) {
      int ent = sidx[i];
      int h = ent >> 1;
      int isP = ent & 1;
      int take = (i < r) ? isP : (1 - isP);
      if (take) {
        float wv = w2[h * H + d];
        accW += w1v[h] * wv;
        accB += b1v[h] * wv;
      }
    }
    ws[WS_TBL + r * 256 + 2 * d + 0] = accW;
    ws[WS_TBL + r * 256 + 2 * d + 1] = accB;
  } else {
    // pack: B-fragment for mfma_f32_16x16x32_bf16:
    // frag (c,kc,lane) elem j = B[k=kc*32+(lane>>4)*8+j][n=c*16+(lane&15)]
    int idx = (blk - 257) * 128 + tid;             // 65536 total
    int j  = idx & 7;
    int l  = (idx >> 3) & 63;
    int kc = (idx >> 9) & 15;
    int c  = idx >> 13;
    int k = kc * 32 + ((l >> 4) * 8) + j;
    int n = c * 16 + (l & 15);
    float x = em_w1[k * H + n];
    unsigned short hb = bfbits(x);
    unsigned short lb = bfbits(x - bf2f(hb));
    ((unsigned short*)(ws + WSB_HI))[idx] = hb;
    ((unsigned short*)(ws + WSB_LO))[idx] = lb;
  }
}

// Attention side-loop, templated on ballot count (NB=2 when M<=128).
// Valid-mask skip: only k with (tm < t) are processed (invalid entries'
// exp(-1e9 - mx) underflows to exactly 0 in the reference, so skipping is
// exact). All-invalid sides (P~5%) fall back to the uniform-1/20 mean.
template<int NB>
__device__ __forceinline__ void run_sides(
    int sbase, int b0, int B, int lane,
    const int* __restrict__ edge_index, const int* __restrict__ edge_ts,
    const int* __restrict__ hist_nb, const int* __restrict__ hist_tm,
    const int* __restrict__ hist_sg,
    const float* __restrict__ node_emb, const float* __restrict__ ws,
    float th0, float th1, float th2, float th3,
    float2 se0, float2 se1, float* __restrict__ zbuf)
{
  int e_n = sbase >> 1, side_n = sbase & 1;
  int node0 = edge_index[side_n * B + (b0 + e_n)];
  int t_n = edge_ts[b0 + e_n];
  float2 q_n = *(const float2*)(node_emb + (size_t)node0 * H + 2 * lane);
  int pk_n = 0, tm_n = 0;
  if (lane < K) {
    int nb = hist_nb[node0 * K + lane];
    int sg = hist_sg[node0 * K + lane];
    tm_n = hist_tm[node0 * K + lane];
    pk_n = (nb << 1) | sg;
  }

  #pragma unroll 1
  for (int i = 0; i < 8; i++) {
    int s = sbase + i;
    int e = s >> 1, side = s & 1;
    int tC = t_n; float2 qC = q_n; int pkC = pk_n, tmC = tm_n;
    if (i < 7) {
      int s2 = s + 1;
      int e2 = s2 >> 1, side2 = s2 & 1;
      int node2 = edge_index[side2 * B + (b0 + e2)];
      t_n = edge_ts[b0 + e2];
      q_n = *(const float2*)(node_emb + (size_t)node2 * H + 2 * lane);
      if (lane < K) {
        int nb = hist_nb[node2 * K + lane];
        int sg = hist_sg[node2 * K + lane];
        tm_n = hist_tm[node2 * K + lane];
        pk_n = (nb << 1) | sg;
      }
    }

    // wave-uniform validity mask over the K history slots
    unsigned long long vmask =
        __ballot((lane < K) && (tmC < tC) && (pkC >= 0));

    float z0 = 0.f, z1 = 0.f;
    if (vmask) {
      // online softmax over valid entries only (~10 avg instead of 20)
      float m1 = -3.0e38f, ssum = 0.f;
      while (vmask) {
        int k = __ffsll((long long)vmask) - 1;          // scalar
        vmask &= vmask - 1;
        int tm_k = __builtin_amdgcn_readlane(tmC, k);
        int pk_k = __builtin_amdgcn_readlane(pkC, k);
        int sg_k = pk_k & 1;
        float dk = (float)tC - (float)tm_k;             // uniform
        int r = __popcll(__ballot(th0 < dk)) + __popcll(__ballot(th1 < dk));
        if (NB == 4)
          r += __popcll(__ballot(th2 < dk)) + __popcll(__ballot(th3 < dk));
        const float4 tb = *(const float4*)(ws + WS_TBL + r * 256 + 4 * lane);
        int nbc = pk_k >> 1;
        float2 ne = *(const float2*)(node_emb + (size_t)nbc * H + 2 * lane);
        float k0 = ne.x + (sg_k ? se1.x : se0.x) + dk * tb.x + tb.y;
        float k1 = ne.y + (sg_k ? se1.y : se0.y) + dk * tb.z + tb.w;
        float p = wave_sum63(qC.x * k0 + qC.y * k1);
        float sck = bcast63(p) * 0.088388347648318447f; // 1/sqrt(128)
        float mn = fmaxf(m1, sck);
        float al = __expf(m1 - mn);
        float pe = __expf(sck - mn);
        ssum = ssum * al + pe;
        z0 = z0 * al + pe * k0;
        z1 = z1 * al + pe * k1;
        m1 = mn;
      }
      float inv = 1.f / ssum;
      z0 *= inv; z1 *= inv;
    } else {
      // all scores -1e9 -> softmax uniform 1/20 over ALL keys
      #pragma unroll 1
      for (int k = 0; k < K; k++) {
        int tm_k = __builtin_amdgcn_readlane(tmC, k);
        int pk_k = __builtin_amdgcn_readlane(pkC, k);
        int sg_k = pk_k & 1;
        float dk = (float)tC - (float)tm_k;
        int r = __popcll(__ballot(th0 < dk)) + __popcll(__ballot(th1 < dk));
        if (NB == 4)
          r += __popcll(__ballot(th2 < dk)) + __popcll(__ballot(th3 < dk));
        const float4 tb = *(const float4*)(ws + WS_TBL + r * 256 + 4 * lane);
        int nbc = (pk_k < 0) ? 0 : (pk_k >> 1);
        float2 ne = *(const float2*)(node_emb + (size_t)nbc * H + 2 * lane);
        z0 += ne.x + (sg_k ? se1.x : se0.x) + dk * tb.x + tb.y;
        z1 += ne.y + (sg_k ? se1.y : se0.y) + dk * tb.z + tb.w;
      }
      z0 *= 0.05f; z1 *= 0.05f;                         // 1/K
    }
    int c = side * 64 + lane;
    int cc = c ^ ((e & 7) << 1);
    *(float2*)&zbuf[(e << 8) + (cc << 1)] = make_float2(z0, z1);
  }
}

// Main fused kernel: 4 waves/block, each wave owns 8 edge-sides in the
// attention phase (lane = dims 2l,2l+1). bounds(256,4): known no-spill
// regime (R11: WRITE_SIZE 0.26 MB, VGPR 64).
// zu/zv XOR-swizzled in 16 KB LDS; MLP layer 1 via split-bf16 MFMA with
// derived columns built on the fly.
__global__ __launch_bounds__(256, 4) void tgat_main_kernel(
    const int* __restrict__ edge_index, const int* __restrict__ edge_ts,
    const int* __restrict__ hist_nb, const int* __restrict__ hist_tm,
    const int* __restrict__ hist_sg,
    const float* __restrict__ node_emb, const float* __restrict__ sign_emb,
    const float* __restrict__ em_b1,
    const float* __restrict__ em_w2, const float* __restrict__ em_b2,
    const float* __restrict__ ws, float* __restrict__ out, int B)
{
  // zbuf rows = 16 edges, 256 floats (zu|zv) per row, float2-chunk XOR swizzle:
  // logical chunk c of row e stored at chunk c ^ ((e&7)<<1). 16 KB total.
  __shared__ __align__(16) float zbuf[EPB * 256];

  int tid = threadIdx.x;
  int lane = tid & 63;
  int wv = __builtin_amdgcn_readfirstlane(tid >> 6);
  int b0 = blockIdx.x * EPB;

  int M = ((const int*)(ws + WS_CNT))[0];
  float th0 = (lane       < M) ? ws[WS_THM + lane      ] : 3.0e38f;
  float th1 = (lane + 64  < M) ? ws[WS_THM + lane + 64 ] : 3.0e38f;
  float2 se0 = *(const float2*)(sign_emb + 2 * lane);
  float2 se1 = *(const float2*)(sign_emb + H + 2 * lane);

  int sbase = wv * 8;
  if (M <= 128) {
    run_sides<2>(sbase, b0, B, lane, edge_index, edge_ts, hist_nb, hist_tm,
                 hist_sg, node_emb, ws, th0, th1, 3.0e38f, 3.0e38f,
                 se0, se1, zbuf);
  } else {
    float th2 = (lane + 128 < M) ? ws[WS_THM + lane + 128] : 3.0e38f;
    float th3 = (lane + 192 < M) ? ws[WS_THM + lane + 192] : 3.0e38f;
    run_sides<4>(sbase, b0, B, lane, edge_index, edge_ts, hist_nb, hist_tm,
                 hist_sg, node_emb, ws, th0, th1, th2, th3,
                 se0, se1, zbuf);
  }
  __syncthreads();

  // ---- MLP layer 1 via split-bf16 MFMA: hid[16][128] = feat[16][512] @ em_w1
  // feat regions: [zu | zv | |zu-zv| | zu*zv], built on the fly from zbuf.
  const unsigned short* whi = (const unsigned short*)(ws + WSB_HI);
  const unsigned short* wlo = (const unsigned short*)(ws + WSB_LO);
  int c0 = 2 * wv;
  int m_ = lane & 15;
  int qd = lane >> 4;
  int sw = (m_ & 7) << 1;
  const float* zrow = zbuf + (m_ << 8);
  f32x4 acc0 = {0.f, 0.f, 0.f, 0.f};
  f32x4 acc1 = {0.f, 0.f, 0.f, 0.f};
  #pragma unroll
  for (int kc = 0; kc < 16; kc++) {
    const int reg = kc >> 2;
    int cb = (kc & 3) * 16 + qd * 4;     // base chunk within a 128-dim region
    float av[8];
    if (reg == 0) {
      float4 A0 = *(const float4*)(zrow + (((cb    ) ^ sw) << 1));
      float4 A1 = *(const float4*)(zrow + (((cb + 2) ^ sw) << 1));
      av[0]=A0.x; av[1]=A0.y; av[2]=A0.z; av[3]=A0.w;
      av[4]=A1.x; av[5]=A1.y; av[6]=A1.z; av[7]=A1.w;
    } else if (reg == 1) {
      float4 A0 = *(const float4*)(zrow + (((cb + 64) ^ sw) << 1));
      float4 A1 = *(const float4*)(zrow + (((cb + 66) ^ sw) << 1));
      av[0]=A0.x; av[1]=A0.y; av[2]=A0.z; av[3]=A0.w;
      av[4]=A1.x; av[5]=A1.y; av[6]=A1.z; av[7]=A1.w;
    } else {
      float4 U0 = *(const float4*)(zrow + (((cb    ) ^ sw) << 1));
      float4 U1 = *(const float4*)(zrow + (((cb + 2) ^ sw) << 1));
      float4 V0 = *(const float4*)(zrow + (((cb + 64) ^ sw) << 1));
      float4 V1 = *(const float4*)(zrow + (((cb + 66) ^ sw) << 1));
      float uu[8] = {U0.x,U0.y,U0.z,U0.w,U1.x,U1.y,U1.z,U1.w};
      float vvv[8] = {V0.x,V0.y,V0.z,V0.w,V1.x,V1.y,V1.z,V1.w};
      if (reg == 2) {
        #pragma unroll
        for (int j = 0; j < 8; j++) av[j] = fabsf(uu[j] - vvv[j]);
      } else {
        #pragma unroll
        for (int j = 0; j < 8; j++) av[j] = uu[j] * vvv[j];
      }
    }
    union { short8 v; unsigned short u[8]; } ahi, alo;
    #pragma unroll
    for (int j = 0; j < 8; j++) {
      unsigned short hb = bfbits(av[j]);
      ahi.u[j] = hb;
      alo.u[j] = bfbits(av[j] - bf2f(hb));
    }
    int f0 = (((c0    ) * 16 + kc) * 64 + lane) * 8;
    int f1 = (((c0 + 1) * 16 + kc) * 64 + lane) * 8;
    short8 bh0 = *(const short8*)(whi + f0);
    short8 bl0 = *(const short8*)(wlo + f0);
    short8 bh1 = *(const short8*)(whi + f1);
    short8 bl1 = *(const short8*)(wlo + f1);
    acc0 = __builtin_amdgcn_mfma_f32_16x16x32_bf16(ahi.v, bh0, acc0, 0, 0, 0);
    acc0 = __builtin_amdgcn_mfma_f32_16x16x32_bf16(ahi.v, bl0, acc0, 0, 0, 0);
    acc0 = __builtin_amdgcn_mfma_f32_16x16x32_bf16(alo.v, bh0, acc0, 0, 0, 0);
    acc1 = __builtin_amdgcn_mfma_f32_16x16x32_bf16(ahi.v, bh1, acc1, 0, 0, 0);
    acc1 = __builtin_amdgcn_mfma_f32_16x16x32_bf16(ahi.v, bl1, acc1, 0, 0, 0);
    acc1 = __builtin_amdgcn_mfma_f32_16x16x32_bf16(alo.v, bh1, acc1, 0, 0, 0);
  }
  __syncthreads();   // all A-reads of zbuf complete before overlay reuse

  // bias + relu, write hid into zbuf overlay (stride 132)
  float* hp = zbuf;
  float eb0 = em_b1[c0 * 16 + m_];
  float eb1 = em_b1[(c0 + 1) * 16 + m_];
  #pragma unroll
  for (int r = 0; r < 4; r++) {
    int edge = qd * 4 + r;
    hp[edge * 132 + c0 * 16 + m_]       = fmaxf(acc0[r] + eb0, 0.f);
    hp[edge * 132 + (c0 + 1) * 16 + m_] = fmaxf(acc1[r] + eb1, 0.f);
  }
  __syncthreads();

  // ---- layer 2: logits = hid @ em_w2 + em_b2 ; wave wv does edges wv*4..+3
  float2 w2v = *(const float2*)(em_w2 + 2 * lane);
  float bias2 = em_b2[0];
  #pragma unroll
  for (int i = 0; i < 4; i++) {
    int e = wv * 4 + i;
    int b = b0 + e;
    float2 hv = *(const float2*)(hp + e * 132 + 2 * lane);
    float p = wave_sum63(hv.x * w2v.x + hv.y * w2v.y);
    float ps = bcast63(p);
    if (lane == 0 && b < B) out[b] = ps + bias2;
  }
}

extern "C" void kernel_launch(void* const* d_in, const int* in_sizes, int n_in,
                              void* d_out, int out_size, void* d_ws, size_t ws_size,
                              hipStream_t stream)
{
  (void)n_in; (void)out_size; (void)ws_size;
  const int* edge_index = (const int*)d_in[0];
  const int* edge_ts    = (const int*)d_in[1];
  const int* hist_nb    = (const int*)d_in[2];
  const int* hist_tm    = (const int*)d_in[3];
  const int* hist_sg    = (const int*)d_in[4];
  const float* node_emb = (const float*)d_in[5];
  const float* sign_emb = (const float*)d_in[6];
  const float* tp_w1    = (const float*)d_in[7];
  const float* tp_b1    = (const float*)d_in[8];
  const float* tp_w2    = (const float*)d_in[9];
  const float* tp_b2    = (const float*)d_in[10];
  const float* em_w1    = (const float*)d_in[11];
  const float* em_b1    = (const float*)d_in[12];
  const float* em_w2    = (const float*)d_in[13];
  const float* em_b2    = (const float*)d_in[14];
  float* out = (float*)d_out;
  float* ws  = (float*)d_ws;
  int B = in_sizes[1];

  hipLaunchKernelGGL(aux_kernel, dim3(769), dim3(128), 0, stream,
                     tp_w1, tp_b1, tp_w2, tp_b2, em_w1, ws);
  int grid = (B + EPB - 1) / EPB;
  hipLaunchKernelGGL(tgat_main_kernel, dim3(grid), dim3(256), 0, stream,
                     edge_index, edge_ts, hist_nb, hist_tm, hist_sg,
                     node_emb, sign_emb, em_b1, em_w2, em_b2, ws, out, B);
}

// Round 13
// 391.040 us; speedup vs baseline: 1.1397x; 1.1397x over previous
//
#include <hip/hip_runtime.h>
#include <hip/hip_bf16.h>
#include <math.h>

#define H 128
#define K 20
#define EPB 16        // edges per block (M=16 for MFMA)

// ---- workspace layout (float offsets) ----
#define WS_TBL    0            // merged table: 257 rows x 256 floats {W,B}
#define WS_THM    65792        // 256 merged sorted thresholds
#define WS_CNT    66176        // 1 int: M = nP + nN
#define WSB_HI    67072        // 65536 ushort: em_w1 bf16-hi, B-fragment order
#define WSB_LO    99840        // 65536 ushort: em_w1 bf16-lo

typedef __attribute__((ext_vector_type(8))) short short8;
typedef __attribute__((ext_vector_type(4))) float f32x4;

// DPP-based wave64 sum; result valid in lane 63.
template<int CTRL, int RMASK>
__device__ __forceinline__ float dpp_add(float x) {
  int y = __builtin_amdgcn_update_dpp(0, __float_as_int(x), CTRL, RMASK, 0xf, true);
  return x + __int_as_float(y);
}
__device__ __forceinline__ float wave_sum63(float x) {
  x = dpp_add<0xB1,  0xf>(x);
  x = dpp_add<0x4E,  0xf>(x);
  x = dpp_add<0x141, 0xf>(x);
  x = dpp_add<0x140, 0xf>(x);
  x = dpp_add<0x142, 0xa>(x);
  x = dpp_add<0x143, 0xc>(x);
  return x;
}
__device__ __forceinline__ float bcast63(float x) {
  return __int_as_float(__builtin_amdgcn_readlane(__float_as_int(x), 63));
}

__device__ __forceinline__ unsigned short bfbits(float x) {
  __hip_bfloat16 h = __float2bfloat16(x);
  unsigned short u; __builtin_memcpy(&u, &h, 2); return u;
}
__device__ __forceinline__ float bf2f(unsigned short u) {
  return __uint_as_float(((unsigned)u) << 16);
}

// Single fused aux kernel (769 blocks x 128 threads):
//  blocks 0..256  : locally recompute the threshold sort, then build merged-
//                   table row r = blockIdx (block 0 also publishes THM/CNT).
//  blocks 257..768: pack em_w1 into bf16 hi/lo planes, B-fragment order.
__global__ __launch_bounds__(128) void aux_kernel(
    const float* __restrict__ w1v, const float* __restrict__ b1v,
    const float* __restrict__ w2, const float* __restrict__ b2,
    const float* __restrict__ em_w1, float* __restrict__ ws)
{
  int blk = blockIdx.x;
  int tid = threadIdx.x;
  if (blk < 257) {
    __shared__ float th[H];
    __shared__ int grp[H];
    __shared__ int sidx[2 * H];
    __shared__ int Msh;
    float w = w1v[tid], b = b1v[tid];
    int g = (w > 0.f) ? 0 : ((w < 0.f) ? 1 : 2);   // 0=P, 1=N, 2=Z
    float t = (g == 2) ? 0.f : (-b / w);
    th[tid] = t; grp[tid] = g;
    if (tid == 0) Msh = 0;
    __syncthreads();
    if (g != 2) {
      int r = 0;
      for (int i = 0; i < H; i++)
        if (grp[i] != 2 && (th[i] < t || (th[i] == t && i < tid))) r++;
      sidx[r] = (tid << 1) | (g == 0 ? 1 : 0);     // bit0 = isP
      atomicAdd(&Msh, 1);
      if (blk == 0) ws[WS_THM + r] = t;            // publish for main
    }
    __syncthreads();
    int M = Msh;
    if (blk == 0 && tid == 0) ((int*)(ws + WS_CNT))[0] = M;
    int r = blk;
    if (r > M) return;
    int d = tid;
    // BASE[d] = tp_b2[d] + sum over (w1==0, b1>0) of b1*w2[h][d]
    float accW = 0.f, accB = b2[d];
    for (int i = 0; i < H; i++)
      if (grp[i] == 2 && b1v[i] > 0.f) accB += b1v[i] * w2[i * H + d];
    #pragma unroll 4
    for (int i = 0; i < M; i++) {
      int ent = sidx[i];
      int h = ent >> 1;
      int isP = ent & 1;
      int take = (i < r) ? isP : (1 - isP);
      if (take) {
        float wv = w2[h * H + d];
        accW += w1v[h] * wv;
        accB += b1v[h] * wv;
      }
    }
    ws[WS_TBL + r * 256 + 2 * d + 0] = accW;
    ws[WS_TBL + r * 256 + 2 * d + 1] = accB;
  } else {
    // pack: B-fragment for mfma_f32_16x16x32_bf16:
    // frag (c,kc,lane) elem j = B[k=kc*32+(lane>>4)*8+j][n=c*16+(lane&15)]
    int idx = (blk - 257) * 128 + tid;             // 65536 total
    int j  = idx & 7;
    int l  = (idx >> 3) & 63;
    int kc = (idx >> 9) & 15;
    int c  = idx >> 13;
    int k = kc * 32 + ((l >> 4) * 8) + j;
    int n = c * 16 + (l & 15);
    float x = em_w1[k * H + n];
    unsigned short hb = bfbits(x);
    unsigned short lb = bfbits(x - bf2f(hb));
    ((unsigned short*)(ws + WSB_HI))[idx] = hb;
    ((unsigned short*)(ws + WSB_LO))[idx] = lb;
  }
}

// Attention: each wave owns 4 EDGES; both sides (u,v) of an edge are
// processed CONCURRENTLY in straight-line code (2 independent dependency
// chains -> 2x memory/ALU latency overlap). Valid-mask skip per side;
// exhausted side runs dummy iterations whose pe underflows to exactly 0.
template<int NB>
__device__ __forceinline__ void run_sides(
    int sbase, int b0, int B, int lane,
    const int* __restrict__ edge_index, const int* __restrict__ edge_ts,
    const int* __restrict__ hist_nb, const int* __restrict__ hist_tm,
    const int* __restrict__ hist_sg,
    const float* __restrict__ node_emb, const float* __restrict__ ws,
    float th0, float th1, float th2, float th3,
    float2 se0, float2 se1, float* __restrict__ zbuf)
{
  const float S = 0.088388347648318447f;   // 1/sqrt(128)
  int eBase = sbase >> 1;                  // 4 edges per wave
  // ---- prefetch edge eBase (both sides) ----
  int eN = b0 + eBase;
  int nU = edge_index[eN];
  int nV = edge_index[B + eN];
  int t_n = edge_ts[eN];
  float2 qU_n = *(const float2*)(node_emb + (size_t)nU * H + 2 * lane);
  float2 qV_n = *(const float2*)(node_emb + (size_t)nV * H + 2 * lane);
  int pkU_n = 0, tmU_n = 0, pkV_n = 0, tmV_n = 0;
  if (lane < K) {
    pkU_n = (hist_nb[nU * K + lane] << 1) | hist_sg[nU * K + lane];
    tmU_n = hist_tm[nU * K + lane];
    pkV_n = (hist_nb[nV * K + lane] << 1) | hist_sg[nV * K + lane];
    tmV_n = hist_tm[nV * K + lane];
  }

  #pragma unroll 1
  for (int p = 0; p < 4; p++) {
    int e = eBase + p;
    int tC = t_n;
    float2 qU = qU_n, qV = qV_n;
    int pkU = pkU_n, tmU = tmU_n, pkV = pkV_n, tmV = tmV_n;
    if (p < 3) {
      int e2 = b0 + e + 1;
      int nU2 = edge_index[e2];
      int nV2 = edge_index[B + e2];
      t_n = edge_ts[e2];
      qU_n = *(const float2*)(node_emb + (size_t)nU2 * H + 2 * lane);
      qV_n = *(const float2*)(node_emb + (size_t)nV2 * H + 2 * lane);
      if (lane < K) {
        pkU_n = (hist_nb[nU2 * K + lane] << 1) | hist_sg[nU2 * K + lane];
        tmU_n = hist_tm[nU2 * K + lane];
        pkV_n = (hist_nb[nV2 * K + lane] << 1) | hist_sg[nV2 * K + lane];
        tmV_n = hist_tm[nV2 * K + lane];
      }
    }

    unsigned long long mU0 = __ballot((lane < K) && (tmU < tC) && (pkU >= 0));
    unsigned long long mV0 = __ballot((lane < K) && (tmV < tC) && (pkV >= 0));
    float qUx = qU.x * S, qUy = qU.y * S;
    float qVx = qV.x * S, qVy = qV.y * S;

    float mxU = -3.0e38f, ssU = 0.f, zU0 = 0.f, zU1 = 0.f;
    float mxV = -3.0e38f, ssV = 0.f, zV0 = 0.f, zV1 = 0.f;
    unsigned long long mU = mU0, mV = mV0;
    while (mU | mV) {
      int kU = mU ? (__ffsll((long long)mU) - 1) : 0;
      int kV = mV ? (__ffsll((long long)mV) - 1) : 0;
      bool vU = mU != 0, vV = mV != 0;
      mU &= mU - 1; mV &= mV - 1;
      int tmkU = __builtin_amdgcn_readlane(tmU, kU);
      int pkkU = __builtin_amdgcn_readlane(pkU, kU);
      int tmkV = __builtin_amdgcn_readlane(tmV, kV);
      int pkkV = __builtin_amdgcn_readlane(pkV, kV);
      float dkU = (float)tC - (float)tmkU;
      float dkV = (float)tC - (float)tmkV;
      int rU = __popcll(__ballot(th0 < dkU)) + __popcll(__ballot(th1 < dkU));
      int rV = __popcll(__ballot(th0 < dkV)) + __popcll(__ballot(th1 < dkV));
      if (NB == 4) {
        rU += __popcll(__ballot(th2 < dkU)) + __popcll(__ballot(th3 < dkU));
        rV += __popcll(__ballot(th2 < dkV)) + __popcll(__ballot(th3 < dkV));
      }
      const float4 tbU = *(const float4*)(ws + WS_TBL + rU * 256 + 4 * lane);
      const float4 tbV = *(const float4*)(ws + WS_TBL + rV * 256 + 4 * lane);
      int nbU = (pkkU < 0) ? 0 : (pkkU >> 1);
      int nbV = (pkkV < 0) ? 0 : (pkkV >> 1);
      float2 neU = *(const float2*)(node_emb + (size_t)nbU * H + 2 * lane);
      float2 neV = *(const float2*)(node_emb + (size_t)nbV * H + 2 * lane);
      float kU0 = neU.x + ((pkkU & 1) ? se1.x : se0.x) + dkU * tbU.x + tbU.y;
      float kU1 = neU.y + ((pkkU & 1) ? se1.y : se0.y) + dkU * tbU.z + tbU.w;
      float kV0 = neV.x + ((pkkV & 1) ? se1.x : se0.x) + dkV * tbV.x + tbV.y;
      float kV1 = neV.y + ((pkkV & 1) ? se1.y : se0.y) + dkV * tbV.z + tbV.w;
      float pU = wave_sum63(qUx * kU0 + qUy * kU1);
      float pV = wave_sum63(qVx * kV0 + qVy * kV1);
      float sU = vU ? bcast63(pU) : -1e9f;
      float sV = vV ? bcast63(pV) : -1e9f;
      float mnU = fmaxf(mxU, sU);
      float alU = __expf(mxU - mnU), peU = __expf(sU - mnU);
      ssU = ssU * alU + peU;
      zU0 = zU0 * alU + peU * kU0;
      zU1 = zU1 * alU + peU * kU1;
      mxU = mnU;
      float mnV = fmaxf(mxV, sV);
      float alV = __expf(mxV - mnV), peV = __expf(sV - mnV);
      ssV = ssV * alV + peV;
      zV0 = zV0 * alV + peV * kV0;
      zV1 = zV1 * alV + peV * kV1;
      mxV = mnV;
    }

    // normalize / fallback (fallback = uniform 1/20 over all keys, rare ~5%)
    if (mU0) {
      float inv = 1.f / ssU; zU0 *= inv; zU1 *= inv;
    } else {
      zU0 = 0.f; zU1 = 0.f;
      #pragma unroll 1
      for (int k = 0; k < K; k++) {
        int tm_k = __builtin_amdgcn_readlane(tmU, k);
        int pk_k = __builtin_amdgcn_readlane(pkU, k);
        float dk = (float)tC - (float)tm_k;
        int r = __popcll(__ballot(th0 < dk)) + __popcll(__ballot(th1 < dk));
        if (NB == 4)
          r += __popcll(__ballot(th2 < dk)) + __popcll(__ballot(th3 < dk));
        const float4 tb = *(const float4*)(ws + WS_TBL + r * 256 + 4 * lane);
        int nbc = (pk_k < 0) ? 0 : (pk_k >> 1);
        float2 ne = *(const float2*)(node_emb + (size_t)nbc * H + 2 * lane);
        zU0 += ne.x + ((pk_k & 1) ? se1.x : se0.x) + dk * tb.x + tb.y;
        zU1 += ne.y + ((pk_k & 1) ? se1.y : se0.y) + dk * tb.z + tb.w;
      }
      zU0 *= 0.05f; zU1 *= 0.05f;
    }
    if (mV0) {
      float inv = 1.f / ssV; zV0 *= inv; zV1 *= inv;
    } else {
      zV0 = 0.f; zV1 = 0.f;
      #pragma unroll 1
      for (int k = 0; k < K; k++) {
        int tm_k = __builtin_amdgcn_readlane(tmV, k);
        int pk_k = __builtin_amdgcn_readlane(pkV, k);
        float dk = (float)tC - (float)tm_k;
        int r = __popcll(__ballot(th0 < dk)) + __popcll(__ballot(th1 < dk));
        if (NB == 4)
          r += __popcll(__ballot(th2 < dk)) + __popcll(__ballot(th3 < dk));
        const float4 tb = *(const float4*)(ws + WS_TBL + r * 256 + 4 * lane);
        int nbc = (pk_k < 0) ? 0 : (pk_k >> 1);
        float2 ne = *(const float2*)(node_emb + (size_t)nbc * H + 2 * lane);
        zV0 += ne.x + ((pk_k & 1) ? se1.x : se0.x) + dk * tb.x + tb.y;
        zV1 += ne.y + ((pk_k & 1) ? se1.y : se0.y) + dk * tb.z + tb.w;
      }
      zV0 *= 0.05f; zV1 *= 0.05f;
    }

    int sw = (e & 7) << 1;
    int ccU = lane ^ sw;
    int ccV = (64 + lane) ^ sw;
    *(float2*)&zbuf[(e << 8) + (ccU << 1)] = make_float2(zU0, zU1);
    *(float2*)&zbuf[(e << 8) + (ccV << 1)] = make_float2(zV0, zV1);
  }
}

// Main fused kernel: 4 waves/block, each wave owns 4 edges (8 sides) with
// dual-side ILP in the attention phase (lane = dims 2l,2l+1).
// bounds(256,4): known no-spill regime. zu/zv XOR-swizzled in 16 KB LDS;
// MLP layer 1 via split-bf16 MFMA with derived columns built on the fly.
__global__ __launch_bounds__(256, 4) void tgat_main_kernel(
    const int* __restrict__ edge_index, const int* __restrict__ edge_ts,
    const int* __restrict__ hist_nb, const int* __restrict__ hist_tm,
    const int* __restrict__ hist_sg,
    const float* __restrict__ node_emb, const float* __restrict__ sign_emb,
    const float* __restrict__ em_b1,
    const float* __restrict__ em_w2, const float* __restrict__ em_b2,
    const float* __restrict__ ws, float* __restrict__ out, int B)
{
  // zbuf rows = 16 edges, 256 floats (zu|zv) per row, float2-chunk XOR swizzle:
  // logical chunk c of row e stored at chunk c ^ ((e&7)<<1). 16 KB total.
  __shared__ __align__(16) float zbuf[EPB * 256];

  int tid = threadIdx.x;
  int lane = tid & 63;
  int wv = __builtin_amdgcn_readfirstlane(tid >> 6);
  int b0 = blockIdx.x * EPB;

  int M = ((const int*)(ws + WS_CNT))[0];
  float th0 = (lane       < M) ? ws[WS_THM + lane      ] : 3.0e38f;
  float th1 = (lane + 64  < M) ? ws[WS_THM + lane + 64 ] : 3.0e38f;
  float2 se0 = *(const float2*)(sign_emb + 2 * lane);
  float2 se1 = *(const float2*)(sign_emb + H + 2 * lane);

  int sbase = wv * 8;
  if (M <= 128) {
    run_sides<2>(sbase, b0, B, lane, edge_index, edge_ts, hist_nb, hist_tm,
                 hist_sg, node_emb, ws, th0, th1, 3.0e38f, 3.0e38f,
                 se0, se1, zbuf);
  } else {
    float th2 = (lane + 128 < M) ? ws[WS_THM + lane + 128] : 3.0e38f;
    float th3 = (lane + 192 < M) ? ws[WS_THM + lane + 192] : 3.0e38f;
    run_sides<4>(sbase, b0, B, lane, edge_index, edge_ts, hist_nb, hist_tm,
                 hist_sg, node_emb, ws, th0, th1, th2, th3,
                 se0, se1, zbuf);
  }
  __syncthreads();

  // ---- MLP layer 1 via split-bf16 MFMA: hid[16][128] = feat[16][512] @ em_w1
  // feat regions: [zu | zv | |zu-zv| | zu*zv], built on the fly from zbuf.
  const unsigned short* whi = (const unsigned short*)(ws + WSB_HI);
  const unsigned short* wlo = (const unsigned short*)(ws + WSB_LO);
  int c0 = 2 * wv;
  int m_ = lane & 15;
  int qd = lane >> 4;
  int sw = (m_ & 7) << 1;
  const float* zrow = zbuf + (m_ << 8);
  f32x4 acc0 = {0.f, 0.f, 0.f, 0.f};
  f32x4 acc1 = {0.f, 0.f, 0.f, 0.f};
  #pragma unroll
  for (int kc = 0; kc < 16; kc++) {
    const int reg = kc >> 2;
    int cb = (kc & 3) * 16 + qd * 4;     // base chunk within a 128-dim region
    float av[8];
    if (reg == 0) {
      float4 A0 = *(const float4*)(zrow + (((cb    ) ^ sw) << 1));
      float4 A1 = *(const float4*)(zrow + (((cb + 2) ^ sw) << 1));
      av[0]=A0.x; av[1]=A0.y; av[2]=A0.z; av[3]=A0.w;
      av[4]=A1.x; av[5]=A1.y; av[6]=A1.z; av[7]=A1.w;
    } else if (reg == 1) {
      float4 A0 = *(const float4*)(zrow + (((cb + 64) ^ sw) << 1));
      float4 A1 = *(const float4*)(zrow + (((cb + 66) ^ sw) << 1));
      av[0]=A0.x; av[1]=A0.y; av[2]=A0.z; av[3]=A0.w;
      av[4]=A1.x; av[5]=A1.y; av[6]=A1.z; av[7]=A1.w;
    } else {
      float4 U0 = *(const float4*)(zrow + (((cb    ) ^ sw) << 1));
      float4 U1 = *(const float4*)(zrow + (((cb + 2) ^ sw) << 1));
      float4 V0 = *(const float4*)(zrow + (((cb + 64) ^ sw) << 1));
      float4 V1 = *(const float4*)(zrow + (((cb + 66) ^ sw) << 1));
      float uu[8] = {U0.x,U0.y,U0.z,U0.w,U1.x,U1.y,U1.z,U1.w};
      float vvv[8] = {V0.x,V0.y,V0.z,V0.w,V1.x,V1.y,V1.z,V1.w};
      if (reg == 2) {
        #pragma unroll
        for (int j = 0; j < 8; j++) av[j] = fabsf(uu[j] - vvv[j]);
      } else {
        #pragma unroll
        for (int j = 0; j < 8; j++) av[j] = uu[j] * vvv[j];
      }
    }
    union { short8 v; unsigned short u[8]; } ahi, alo;
    #pragma unroll
    for (int j = 0; j < 8; j++) {
      unsigned short hb = bfbits(av[j]);
      ahi.u[j] = hb;
      alo.u[j] = bfbits(av[j] - bf2f(hb));
    }
    int f0 = (((c0    ) * 16 + kc) * 64 + lane) * 8;
    int f1 = (((c0 + 1) * 16 + kc) * 64 + lane) * 8;
    short8 bh0 = *(const short8*)(whi + f0);
    short8 bl0 = *(const short8*)(wlo + f0);
    short8 bh1 = *(const short8*)(whi + f1);
    short8 bl1 = *(const short8*)(wlo + f1);
    acc0 = __builtin_amdgcn_mfma_f32_16x16x32_bf16(ahi.v, bh0, acc0, 0, 0, 0);
    acc0 = __builtin_amdgcn_mfma_f32_16x16x32_bf16(ahi.v, bl0, acc0, 0, 0, 0);
    acc0 = __builtin_amdgcn_mfma_f32_16x16x32_bf16(alo.v, bh0, acc0, 0, 0, 0);
    acc1 = __builtin_amdgcn_mfma_f32_16x16x32_bf16(ahi.v, bh1, acc1, 0, 0, 0);
    acc1 = __builtin_amdgcn_mfma_f32_16x16x32_bf16(ahi.v, bl1, acc1, 0, 0, 0);
    acc1 = __builtin_amdgcn_mfma_f32_16x16x32_bf16(alo.v, bh1, acc1, 0, 0, 0);
  }
  __syncthreads();   // all A-reads of zbuf complete before overlay reuse

  // bias + relu, write hid into zbuf overlay (stride 132)
  float* hp = zbuf;
  float eb0 = em_b1[c0 * 16 + m_];
  float eb1 = em_b1[(c0 + 1) * 16 + m_];
  #pragma unroll
  for (int r = 0; r < 4; r++) {
    int edge = qd * 4 + r;
    hp[edge * 132 + c0 * 16 + m_]       = fmaxf(acc0[r] + eb0, 0.f);
    hp[edge * 132 + (c0 + 1) * 16 + m_] = fmaxf(acc1[r] + eb1, 0.f);
  }
  __syncthreads();

  // ---- layer 2: logits = hid @ em_w2 + em_b2 ; wave wv does edges wv*4..+3
  float2 w2v = *(const float2*)(em_w2 + 2 * lane);
  float bias2 = em_b2[0];
  #pragma unroll
  for (int i = 0; i < 4; i++) {
    int e = wv * 4 + i;
    int b = b0 + e;
    float2 hv = *(const float2*)(hp + e * 132 + 2 * lane);
    float p = wave_sum63(hv.x * w2v.x + hv.y * w2v.y);
    float ps = bcast63(p);
    if (lane == 0 && b < B) out[b] = ps + bias2;
  }
}

extern "C" void kernel_launch(void* const* d_in, const int* in_sizes, int n_in,
                              void* d_out, int out_size, void* d_ws, size_t ws_size,
                              hipStream_t stream)
{
  (void)n_in; (void)out_size; (void)ws_size;
  const int* edge_index = (const int*)d_in[0];
  const int* edge_ts    = (const int*)d_in[1];
  const int* hist_nb    = (const int*)d_in[2];
  const int* hist_tm    = (const int*)d_in[3];
  const int* hist_sg    = (const int*)d_in[4];
  const float* node_emb = (const float*)d_in[5];
  const float* sign_emb = (const float*)d_in[6];
  const float* tp_w1    = (const float*)d_in[7];
  const float* tp_b1    = (const float*)d_in[8];
  const float* tp_w2    = (const float*)d_in[9];
  const float* tp_b2    = (const float*)d_in[10];
  const float* em_w1    = (const float*)d_in[11];
  const float* em_b1    = (const float*)d_in[12];
  const float* em_w2    = (const float*)d_in[13];
  const float* em_b2    = (const float*)d_in[14];
  float* out = (float*)d_out;
  float* ws  = (float*)d_ws;
  int B = in_sizes[1];

  hipLaunchKernelGGL(aux_kernel, dim3(769), dim3(128), 0, stream,
                     tp_w1, tp_b1, tp_w2, tp_b2, em_w1, ws);
  int grid = (B + EPB - 1) / EPB;
  hipLaunchKernelGGL(tgat_main_kernel, dim3(grid), dim3(256), 0, stream,
                     edge_index, edge_ts, hist_nb, hist_tm, hist_sg,
                     node_emb, sign_emb, em_b1, em_w2, em_b2, ws, out, B);
}